// Round 1
// baseline (408.926 us; speedup 1.0000x reference)
//
#include <hip/hip_runtime.h>

#define N_NODES 207
#define N_EDGES 1722
#define N_SLOTS 288
#define L_DIM   64
#define C_DIM   2

// ---------------------------------------------------------------------------
// Kernel 1: build CSR adjacency from the (batch-invariant) edge list.
// Runs every launch (ws is re-poisoned). Single block, trivial cost.
// ws layout: [0..207] int row_start (208 ints), then int2 adj[3444] at +832B.
// Self-loop edges (i==j) appear twice in adj[i] -> multiplicity 2, matching
// A[i,i] += 2w in the reference.
// ---------------------------------------------------------------------------
__global__ __launch_bounds__(256) void build_csr_kernel(
    const int* __restrict__ edge_i, const int* __restrict__ edge_j,
    int* __restrict__ row_start, int2* __restrict__ adj) {
    __shared__ int cnt[N_NODES];
    __shared__ int rs[N_NODES + 1];
    const int tid = threadIdx.x;

    for (int n = tid; n < N_NODES; n += blockDim.x) cnt[n] = 0;
    __syncthreads();
    for (int e = tid; e < N_EDGES; e += blockDim.x) {
        atomicAdd(&cnt[edge_i[e]], 1);
        atomicAdd(&cnt[edge_j[e]], 1);
    }
    __syncthreads();
    if (tid == 0) {
        int acc = 0;
        for (int n = 0; n < N_NODES; ++n) { rs[n] = acc; acc += cnt[n]; }
        rs[N_NODES] = acc;   // == 2*N_EDGES
    }
    __syncthreads();
    for (int n = tid; n <= N_NODES; n += blockDim.x) row_start[n] = rs[n];
    for (int n = tid; n < N_NODES; n += blockDim.x) cnt[n] = rs[n]; // running offsets
    __syncthreads();
    for (int e = tid; e < N_EDGES; e += blockDim.x) {
        const int i = edge_i[e], j = edge_j[e];
        int p = atomicAdd(&cnt[i], 1);
        adj[p] = make_int2(j, e);
        int q = atomicAdd(&cnt[j], 1);
        adj[q] = make_int2(i, e);
    }
}

// ---------------------------------------------------------------------------
// Kernel 2: one block per batch element.
//   out[b,n,l] = (1 + wsl[s,n] + deg) * x[b,n,l] - sum_{(m,e) in adj(n)} w[e]*x[b,m,l]
//               + bias[s,n],   with deg = sum_{(m,e) in adj(n)} w[e],  s = ind[b]
// x[b] (53 KB) and w[s] (6.9 KB) staged in LDS; wave = one node (lane = l).
// ---------------------------------------------------------------------------
__global__ __launch_bounds__(256) void diffusion_gcn_kernel(
    const float* __restrict__ inputs,          // (B, 2, 207, 64)
    const float* __restrict__ weight_diff,     // (288, 1722)
    const float* __restrict__ bias_diffusion,  // (288, 207)
    const float* __restrict__ weight_self_loop,// (288, 207)
    const int*   __restrict__ ind,             // (B,)
    const int*   __restrict__ row_start,       // (208,)
    const int2*  __restrict__ adj,             // (3444,)
    float* __restrict__ out) {                 // (B, 207, 64)
    __shared__ float xs[N_NODES * L_DIM];      // 52992 B
    __shared__ float ws[N_EDGES];              //  6888 B
    __shared__ int   rs[N_NODES + 1];          //   832 B

    const int b    = blockIdx.x;
    const int tid  = threadIdx.x;
    const int slot = ind[b];

    // Stage x[b, 0, :, :] -> LDS (float4, fully coalesced)
    const float4* xb4 = (const float4*)(inputs + (size_t)b * (C_DIM * N_NODES * L_DIM));
    float4* xs4 = (float4*)xs;
    #pragma unroll 4
    for (int k = tid; k < (N_NODES * L_DIM) / 4; k += 256) xs4[k] = xb4[k];

    // Stage w[slot] -> LDS
    const float* wrow = weight_diff + (size_t)slot * N_EDGES;
    for (int e = tid; e < N_EDGES; e += 256) ws[e] = wrow[e];
    for (int n = tid; n <= N_NODES; n += 256) rs[n] = row_start[n];
    __syncthreads();

    const int lane = tid & 63;
    const int wv   = tid >> 6;                 // 4 waves
    float* ob = out + (size_t)b * (N_NODES * L_DIM);

    for (int n = wv; n < N_NODES; n += 4) {
        const float xn = xs[n * L_DIM + lane];
        float s = 0.f, d = 0.f;
        const int e0 = rs[n], e1 = rs[n + 1];
        for (int k = e0; k < e1; ++k) {
            const int2 a = adj[k];             // wave-uniform, L2-hot
            const float w = ws[a.y];
            d += w;
            s = fmaf(w, xs[a.x * L_DIM + lane], s);
        }
        const float bias = bias_diffusion[slot * N_NODES + n];
        const float sl   = weight_self_loop[slot * N_NODES + n];
        ob[n * L_DIM + lane] = (1.f + sl + d) * xn - s + bias;
    }
}

extern "C" void kernel_launch(void* const* d_in, const int* in_sizes, int n_in,
                              void* d_out, int out_size, void* d_ws, size_t ws_size,
                              hipStream_t stream) {
    const float* inputs           = (const float*)d_in[0];
    const float* weight_diff      = (const float*)d_in[1];
    const float* bias_diffusion   = (const float*)d_in[2];
    const float* weight_self_loop = (const float*)d_in[3];
    const int*   ind              = (const int*)d_in[4];
    const int*   edge_i           = (const int*)d_in[5];
    const int*   edge_j           = (const int*)d_in[6];
    float* out = (float*)d_out;

    const int B = in_sizes[4];                 // 1024

    int*  row_start = (int*)d_ws;              // 208 ints = 832 B (8B aligned)
    int2* adj       = (int2*)((char*)d_ws + 832);

    build_csr_kernel<<<1, 256, 0, stream>>>(edge_i, edge_j, row_start, adj);
    diffusion_gcn_kernel<<<B, 256, 0, stream>>>(
        inputs, weight_diff, bias_diffusion, weight_self_loop,
        ind, row_start, adj, out);
}

// Round 2
// 237.914 us; speedup vs baseline: 1.7188x; 1.7188x over previous
//
#include <hip/hip_runtime.h>

#define N_NODES 207
#define N_EDGES 1722
#define N_SLOTS 288
#define L_DIM   64

// Round-to-nearest f32 -> bf16, returned as f32 bit pattern with low 16 zeroed
// (i.e. the bf16 value's fp32 bits, kept in the HIGH 16 bits).
__device__ __forceinline__ unsigned int f2bf_rtn_bits_hi(float f) {
    unsigned int u = __float_as_uint(f);
    unsigned int r = u + 0x7FFFu + ((u >> 16) & 1u);
    return r & 0xFFFF0000u;
}

// ---------------------------------------------------------------------------
// K1: build CSR from the batch-invariant edge list.
//   row_start[208] ints; csr_packed[3444] uints = (edge_id<<8) | neighbor
//   (neighbor < 207 fits 8 bits; edge_id < 1722 fits 11 bits)
// Self-loop edges (i==j) appear twice in node i's list -> A[i,i] += 2w, matching ref.
// ---------------------------------------------------------------------------
__global__ __launch_bounds__(256) void build_csr_kernel(
    const int* __restrict__ edge_i, const int* __restrict__ edge_j,
    int* __restrict__ row_start, unsigned int* __restrict__ csr_packed) {
    __shared__ int cnt[N_NODES];
    __shared__ int rs[N_NODES + 1];
    const int tid = threadIdx.x;

    for (int n = tid; n < N_NODES; n += 256) cnt[n] = 0;
    __syncthreads();
    for (int e = tid; e < N_EDGES; e += 256) {
        atomicAdd(&cnt[edge_i[e]], 1);
        atomicAdd(&cnt[edge_j[e]], 1);
    }
    __syncthreads();
    if (tid == 0) {
        int acc = 0;
        for (int n = 0; n < N_NODES; ++n) { rs[n] = acc; acc += cnt[n]; }
        rs[N_NODES] = acc;   // == 2*N_EDGES
    }
    __syncthreads();
    for (int n = tid; n <= N_NODES; n += 256) row_start[n] = rs[n];
    for (int n = tid; n < N_NODES; n += 256) cnt[n] = rs[n];
    __syncthreads();
    for (int e = tid; e < N_EDGES; e += 256) {
        const unsigned int i = edge_i[e], j = edge_j[e];
        const unsigned int ep = ((unsigned int)e) << 8;
        int p = atomicAdd(&cnt[i], 1);
        csr_packed[p] = ep | j;
        int q = atomicAdd(&cnt[j], 1);
        csr_packed[q] = ep | i;
    }
}

// ---------------------------------------------------------------------------
// K1b: per (slot, node) precompute coef = 1 + wsl + deg, and carry bias.
// One block per slot. Tiny (288 blocks).
// ---------------------------------------------------------------------------
__global__ __launch_bounds__(256) void coef_kernel(
    const float* __restrict__ weight_diff, const float* __restrict__ bias_diffusion,
    const float* __restrict__ weight_self_loop,
    const int* __restrict__ row_start, const unsigned int* __restrict__ csr_packed,
    float2* __restrict__ coefbias) {
    __shared__ float wrow[N_EDGES];
    const int s = blockIdx.x;
    for (int e = threadIdx.x; e < N_EDGES; e += 256)
        wrow[e] = weight_diff[(size_t)s * N_EDGES + e];
    __syncthreads();
    const int n = threadIdx.x;
    if (n < N_NODES) {
        float d = 0.f;
        const int e0 = row_start[n], e1 = row_start[n + 1];
        for (int k = e0; k < e1; ++k) d += wrow[csr_packed[k] >> 8];
        coefbias[s * N_NODES + n] = make_float2(
            1.f + weight_self_loop[s * N_NODES + n] + d,
            bias_diffusion[s * N_NODES + n]);
    }
}

// ---------------------------------------------------------------------------
// K2: one block (512 thr = 8 waves) per batch element.
//   out[n,l] = coef[s,n]*x[n,l] + bias[s,n] - sum_k w[k]*x[nb[k],l]
// All inner-loop operands live in LDS: packed (bf16 w | nb) per CSR entry,
// bf16 x for the gather term; fp32 x re-read from global (L2-hot) for the
// dominant self term. LDS = 40688 B -> 4 blocks/CU, 32 waves/CU.
// ---------------------------------------------------------------------------
__global__ __launch_bounds__(512, 8) void diffusion_gcn_kernel(
    const float* __restrict__ inputs,          // (B, 2, 207, 64)
    const float* __restrict__ weight_diff,     // (288, 1722)
    const int*   __restrict__ ind,             // (B,)
    const int*   __restrict__ row_start,       // (208,)
    const unsigned int* __restrict__ csr_packed, // (3444,)
    const float2* __restrict__ coefbias,       // (288, 207)
    float* __restrict__ out) {                 // (B, 207, 64)
    __shared__ unsigned short xs[N_NODES * L_DIM];   // 26496 B (bf16)
    __shared__ unsigned int   wnb[2 * N_EDGES];      // 13776 B
    __shared__ unsigned short rs[N_NODES + 1];       //   416 B

    const int b    = blockIdx.x;
    const int tid  = threadIdx.x;
    const int slot = ind[b];

    const float* xb = inputs + (size_t)b * (2 * N_NODES * L_DIM);  // channel 0

    // Stage x (fp32 global, float4) -> bf16 LDS
    const float4* xb4 = (const float4*)xb;
    for (int k = tid; k < (N_NODES * L_DIM) / 4; k += 512) {
        const float4 v = xb4[k];
        const unsigned int lo = (f2bf_rtn_bits_hi(v.x) >> 16) | f2bf_rtn_bits_hi(v.y);
        const unsigned int hi = (f2bf_rtn_bits_hi(v.z) >> 16) | f2bf_rtn_bits_hi(v.w);
        ((uint2*)xs)[k] = make_uint2(lo, hi);
    }
    // Stage packed (bf16 weight | neighbor) per CSR entry
    const float* wrow = weight_diff + (size_t)slot * N_EDGES;
    for (int k = tid; k < 2 * N_EDGES; k += 512) {
        const unsigned int c = csr_packed[k];
        wnb[k] = f2bf_rtn_bits_hi(wrow[c >> 8]) | (c & 255u);
    }
    for (int n = tid; n <= N_NODES; n += 512) rs[n] = (unsigned short)row_start[n];
    __syncthreads();

    const int lane = tid & 63;
    const int wv   = tid >> 6;                 // 8 waves
    float* ob = out + (size_t)b * (N_NODES * L_DIM);

    for (int n = wv; n < N_NODES; n += 8) {
        const int e0 = rs[n], e1 = rs[n + 1];
        float s = 0.f;
        #pragma unroll 4
        for (int k = e0; k < e1; ++k) {
            const unsigned int p = wnb[k];                         // LDS broadcast
            const float w  = __uint_as_float(p & 0xFFFF0000u);     // bf16 weight
            const float xv = __uint_as_float(
                (unsigned int)xs[(p & 255u) * L_DIM + lane] << 16);
            s = fmaf(w, xv, s);
        }
        const float2 cb = coefbias[slot * N_NODES + n];            // uniform, L2-hot
        const float  xg = xb[n * L_DIM + lane];                    // fp32 self term
        ob[n * L_DIM + lane] = fmaf(cb.x, xg, cb.y) - s;
    }
}

extern "C" void kernel_launch(void* const* d_in, const int* in_sizes, int n_in,
                              void* d_out, int out_size, void* d_ws, size_t ws_size,
                              hipStream_t stream) {
    const float* inputs           = (const float*)d_in[0];
    const float* weight_diff      = (const float*)d_in[1];
    const float* bias_diffusion   = (const float*)d_in[2];
    const float* weight_self_loop = (const float*)d_in[3];
    const int*   ind              = (const int*)d_in[4];
    const int*   edge_i           = (const int*)d_in[5];
    const int*   edge_j           = (const int*)d_in[6];
    float* out = (float*)d_out;

    const int B = in_sizes[4];                 // 1024

    // ws layout
    int*          row_start  = (int*)d_ws;                            // 832 B
    unsigned int* csr_packed = (unsigned int*)((char*)d_ws + 832);    // 13776 B
    float2*       coefbias   = (float2*)((char*)d_ws + 14608);        // 476928 B

    build_csr_kernel<<<1, 256, 0, stream>>>(edge_i, edge_j, row_start, csr_packed);
    coef_kernel<<<N_SLOTS, 256, 0, stream>>>(
        weight_diff, bias_diffusion, weight_self_loop, row_start, csr_packed, coefbias);
    diffusion_gcn_kernel<<<B, 512, 0, stream>>>(
        inputs, weight_diff, ind, row_start, csr_packed, coefbias, out);
}